// Round 10
// baseline (85.657 us; speedup 1.0000x reference)
//
#include <hip/hip_runtime.h>
#include <math.h>

#define BB 8
#define NN 2048
#define DD 256
#define NP 2049
#define AVP 2052
#define E1 0.36787944117144233f
#define PADK 40         // LDS f16 row stride (80 B = 5*16B)
#define ITERS 20

typedef _Float16 f16;
typedef __attribute__((ext_vector_type(8))) _Float16 f16x8;
typedef __attribute__((ext_vector_type(4))) float f32x4;
typedef __attribute__((ext_vector_type(2))) float f32x2;

#define DEC0(DW) __builtin_amdgcn_cvt_pk_f32_fp8((int)(DW), false)
#define DEC1(DW) __builtin_amdgcn_cvt_pk_f32_fp8((int)(DW), true)

// ==== fused GEMM: fp32->f16 cvt + norms + MFMA + fp8 K + flags ====
// blockIdx.x = ROW tile (XCD-pinned: xcd = rt), blockIdx.y = COL tile.
__global__ __launch_bounds__(512) void gemm_fused(const float* __restrict__ d1,
                                                  const float* __restrict__ d2,
                                                  unsigned char* __restrict__ Kc,
                                                  int* __restrict__ flags) {
    __shared__ f16 As[256 * PADK];
    __shared__ f16 Bs[256 * PADK];
    __shared__ float nA[256];
    __shared__ float nB[256];
    __shared__ int anyq[4];

    const int b = blockIdx.z;
    const int rt = blockIdx.x, ct = blockIdx.y;
    const int n0 = rt * 256, m0 = ct * 256;
    const int t = threadIdx.x;             // 0..511
    const int wave = t >> 6, lane = t & 63;
    const int wrow = (wave >> 2) * 128;    // 2x4 wave grid: 128x64 out per wave
    const int wcol = (wave & 3) * 64;
    const float* A  = d1 + ((size_t)b * NN + n0) * DD;
    const float* Bm = d2 + ((size_t)b * NN + m0) * DD;

    const int row1 = t >> 2,         qk1 = (t & 3) * 8;   // rows 0..127
    const int row2 = (t + 512) >> 2, qk2 = qk1;           // rows 128..255
    if (t < 4) anyq[t] = 0;
    if (t < 256) nA[t] = 0.f; else nB[t - 256] = 0.f;

    f32x4 zero = {0.f, 0.f, 0.f, 0.f};
    f32x4 acc[8][4];
    #pragma unroll
    for (int i = 0; i < 8; ++i)
        #pragma unroll
        for (int j = 0; j < 4; ++j) acc[i][j] = zero;

    const int rb = lane & 15;
    const int kg = (lane >> 4) * 8;

    for (int k0 = 0; k0 < DD; k0 += 32) {
        // load fp32, convert to f16, accumulate norm partials
        f32x4 a10 = *(const f32x4*)(A  + (size_t)row1 * DD + k0 + qk1);
        f32x4 a11 = *(const f32x4*)(A  + (size_t)row1 * DD + k0 + qk1 + 4);
        f32x4 a20 = *(const f32x4*)(A  + (size_t)row2 * DD + k0 + qk2);
        f32x4 a21 = *(const f32x4*)(A  + (size_t)row2 * DD + k0 + qk2 + 4);
        f32x4 b10 = *(const f32x4*)(Bm + (size_t)row1 * DD + k0 + qk1);
        f32x4 b11 = *(const f32x4*)(Bm + (size_t)row1 * DD + k0 + qk1 + 4);
        f32x4 b20 = *(const f32x4*)(Bm + (size_t)row2 * DD + k0 + qk2);
        f32x4 b21 = *(const f32x4*)(Bm + (size_t)row2 * DD + k0 + qk2 + 4);
        f16x8 ha1, ha2, hb1, hb2;
        #pragma unroll
        for (int e = 0; e < 4; ++e) {
            ha1[e] = (f16)a10[e]; ha1[e + 4] = (f16)a11[e];
            ha2[e] = (f16)a20[e]; ha2[e + 4] = (f16)a21[e];
            hb1[e] = (f16)b10[e]; hb1[e + 4] = (f16)b11[e];
            hb2[e] = (f16)b20[e]; hb2[e + 4] = (f16)b21[e];
        }
        // per-row norm partials from the f16 representations (self-consistent)
        float sa1 = 0.f, sa2 = 0.f, sb1 = 0.f, sb2 = 0.f;
        #pragma unroll
        for (int e = 0; e < 8; ++e) {
            float x1 = (float)ha1[e], x2 = (float)ha2[e];
            float y1 = (float)hb1[e], y2 = (float)hb2[e];
            sa1 = fmaf(x1, x1, sa1); sa2 = fmaf(x2, x2, sa2);
            sb1 = fmaf(y1, y1, sb1); sb2 = fmaf(y2, y2, sb2);
        }
        sa1 += __shfl_xor(sa1, 1); sa1 += __shfl_xor(sa1, 2);
        sa2 += __shfl_xor(sa2, 1); sa2 += __shfl_xor(sa2, 2);
        sb1 += __shfl_xor(sb1, 1); sb1 += __shfl_xor(sb1, 2);
        sb2 += __shfl_xor(sb2, 1); sb2 += __shfl_xor(sb2, 2);

        __syncthreads();
        *(f16x8*)&As[row1 * PADK + qk1] = ha1;
        *(f16x8*)&As[row2 * PADK + qk2] = ha2;
        *(f16x8*)&Bs[row1 * PADK + qk1] = hb1;
        *(f16x8*)&Bs[row2 * PADK + qk2] = hb2;
        if ((t & 3) == 0) {
            atomicAdd(&nA[row1], sa1);
            atomicAdd(&nA[row2], sa2);
            atomicAdd(&nB[row1], sb1);
            atomicAdd(&nB[row2], sb2);
        }
        __syncthreads();

        f16x8 af[8], bf[4];
        #pragma unroll
        for (int i = 0; i < 8; ++i)
            af[i] = *(const f16x8*)&As[(wrow + i * 16 + rb) * PADK + kg];
        #pragma unroll
        for (int j = 0; j < 4; ++j)
            bf[j] = *(const f16x8*)&Bs[(wcol + j * 16 + rb) * PADK + kg];
        // swapped operands: D col(lane&15) = n, D regs = 4 consecutive m
        #pragma unroll
        for (int i = 0; i < 8; ++i)
            #pragma unroll
            for (int j = 0; j < 4; ++j)
                acc[i][j] = __builtin_amdgcn_mfma_f32_16x16x32_f16(bf[j], af[i], acc[i][j], 0, 0, 0);
    }
    __syncthreads();   // norms final

    // ---- epilogue: pack 4 consecutive-m fp8 into dwords ----
    const int mg = (lane >> 4) * 4;
    unsigned int dw[8][4];
    int nzany = 0;
    #pragma unroll
    for (int i = 0; i < 8; ++i) {
        int n = wrow + i * 16 + rb;
        float rn = nA[n];
        #pragma unroll
        for (int j = 0; j < 4; ++j) {
            const f32x4 cn4 = *(const f32x4*)&nB[wcol + j * 16 + mg];
            f32x4 a = acc[i][j];
            float v0 = __expf(-fmaxf(rn + cn4.x - 2.f * a.x, 0.f));
            float v1 = __expf(-fmaxf(rn + cn4.y - 2.f * a.y, 0.f));
            float v2 = __expf(-fmaxf(rn + cn4.z - 2.f * a.z, 0.f));
            float v3 = __expf(-fmaxf(rn + cn4.w - 2.f * a.w, 0.f));
            int p = __builtin_amdgcn_cvt_pk_fp8_f32(v0, v1, 0, false);
            p = __builtin_amdgcn_cvt_pk_fp8_f32(v2, v3, p, true);
            dw[i][j] = (unsigned int)p;
            nzany |= p;
        }
    }
    const int q = (wrow >> 7) * 2 + (wcol >> 7);
    if (nzany) anyq[q] = 1;
    __syncthreads();
    int anyblk = anyq[0] | anyq[1] | anyq[2] | anyq[3];

    if (anyblk) {
        #pragma unroll
        for (int i = 0; i < 8; ++i) {
            int n = wrow + i * 16 + rb;
            unsigned char* orow = Kc + ((size_t)b * NN + n0 + n) * NN + m0 + wcol + mg;
            #pragma unroll
            for (int j = 0; j < 4; ++j)
                *(unsigned int*)(orow + j * 16) = dw[i][j];
        }
    }
    if (t < 4) {
        int ti = rt * 2 + (t >> 1);
        int tj = ct * 2 + (t & 1);
        flags[b * 256 + ti * 16 + tj] = anyq[(t >> 1) * 2 + (t & 1)] ? 1 : 0;
    }
}

// ========== Sinkhorn iterations: one block per batch =================
__global__ __launch_bounds__(1024) void sinkhorn_iter(
    const unsigned char* __restrict__ Kc,
    const int* __restrict__ flags,
    float* __restrict__ av, float* __restrict__ bv)
{
    const int batch = blockIdx.x;
    const int t = threadIdx.x;
    const int lane = t & 63, w = t >> 6;
    __shared__ float a_sh[NN], b_sh[NN], rs_sh[NN];
    __shared__ float p8[128][9];
    __shared__ float wred[16];
    __shared__ float scal[2];
    __shared__ int flg[256];
    __shared__ int rowNZ[16], colNZ[16], anyNZ;

    if (t < 256) flg[t] = flags[batch * 256 + t];
    if (t == 0) anyNZ = 0;
    __syncthreads();
    if (t < 16) {
        int o = 0;
        #pragma unroll
        for (int j = 0; j < 16; ++j) o |= flg[t * 16 + j];
        rowNZ[t] = o;
        if (o) atomicOr(&anyNZ, 1);
    } else if (t < 32) {
        int j = t - 16, o = 0;
        #pragma unroll
        for (int i = 0; i < 16; ++i) o |= flg[i * 16 + j];
        colNZ[j] = o;
    }
    __syncthreads();
    const unsigned char* Kb = Kc + (size_t)batch * NN * NN;
    float* avb = av + (size_t)batch * AVP;
    float* bvb = bv + (size_t)batch * AVP;

    if (!anyNZ) {
        float bMv = 1.f, bcore = 1.f, aNv = 0.f, acore = 0.f;
        for (int it = 0; it < ITERS; ++it) {
            float Sb = 2048.f * bcore + bMv;
            aNv = 2048.f / (E1 * Sb);
            acore = 1.0f / (E1 * bMv);
            float Sa = 2048.f * acore + aNv;
            bcore = 1.0f / (E1 * aNv);
            bMv = 2048.f / (E1 * Sa);
        }
        avb[t] = acore; avb[t + 1024] = acore;
        bvb[t] = bcore; bvb[t + 1024] = bcore;
        if (t == 0) { avb[NN] = aNv; bvb[NN] = bMv; }
        return;
    }

    b_sh[t] = 1.f; b_sh[t + 1024] = 1.f;
    float bMv = 1.f, aNv = 0.f;
    const int r = t >> 3, c8 = (t & 7) * 16;
    __syncthreads();

    for (int it = 0; it < ITERS; ++it) {
        float sb = b_sh[t] + b_sh[t + 1024];
        #pragma unroll
        for (int off = 1; off < 64; off <<= 1) sb += __shfl_xor(sb, off);
        if (lane == 0) wred[w] = sb;
        rs_sh[t] = 0.f; rs_sh[t + 1024] = 0.f;
        __syncthreads();
        if (t == 0) {
            float S = bMv;
            #pragma unroll
            for (int k = 0; k < 16; ++k) S += wred[k];
            scal[0] = 2048.f / (E1 * S);
        }
        __syncthreads();
        aNv = scal[0];

        for (int i = 0; i < 16; ++i) {
            if (!rowNZ[i]) continue;
            float acc = 0.f;
            for (int j = 0; j < 16; ++j) {
                if (!flg[i * 16 + j]) continue;
                const unsigned char* p = Kb + (size_t)(i * 128 + r) * NN + j * 128 + c8;
                uint4 kv = *(const uint4*)p;
                const float* bp = &b_sh[j * 128 + c8];
                unsigned int dwv[4] = {kv.x, kv.y, kv.z, kv.w};
                #pragma unroll
                for (int q = 0; q < 4; ++q) {
                    f32x2 u0 = DEC0(dwv[q]); f32x2 u1 = DEC1(dwv[q]);
                    acc += u0.x * bp[4 * q] + u0.y * bp[4 * q + 1]
                         + u1.x * bp[4 * q + 2] + u1.y * bp[4 * q + 3];
                }
            }
            p8[r][t & 7] = acc;
            __syncthreads();
            if (t < 128) {
                float s = 0.f;
                #pragma unroll
                for (int k = 0; k < 8; ++k) s += p8[t][k];
                rs_sh[i * 128 + t] = s;
            }
            __syncthreads();
        }
        float ebM = E1 * bMv;
        float a0 = 1.0f / (rs_sh[t] + ebM);
        float a1 = 1.0f / (rs_sh[t + 1024] + ebM);
        a_sh[t] = a0; a_sh[t + 1024] = a1;
        float sa = a0 + a1;
        #pragma unroll
        for (int off = 1; off < 64; off <<= 1) sa += __shfl_xor(sa, off);
        if (lane == 0) wred[w] = sa;
        __syncthreads();
        if (t == 0) {
            float S = aNv;
            #pragma unroll
            for (int k = 0; k < 16; ++k) S += wred[k];
            scal[1] = 2048.f / (E1 * S);
        }
        rs_sh[t] = 0.f; rs_sh[t + 1024] = 0.f;
        __syncthreads();

        for (int j = 0; j < 16; ++j) {
            if (!colNZ[j]) continue;
            float acc = 0.f;
            int col = j * 128 + r;
            for (int i = 0; i < 16; ++i) {
                if (!flg[i * 16 + j]) continue;
                #pragma unroll
                for (int e = 0; e < 16; ++e) {
                    int rr2 = i * 128 + c8 + e;
                    f32x2 u = DEC0((unsigned int)Kb[(size_t)rr2 * NN + col]);
                    acc += u.x * a_sh[rr2];
                }
            }
            p8[r][t & 7] = acc;
            __syncthreads();
            if (t < 128) {
                float s = 0.f;
                #pragma unroll
                for (int k = 0; k < 8; ++k) s += p8[t][k];
                rs_sh[j * 128 + t] = s;
            }
            __syncthreads();
        }
        float eaN = E1 * aNv;
        b_sh[t] = 1.0f / (rs_sh[t] + eaN);
        b_sh[t + 1024] = 1.0f / (rs_sh[t + 1024] + eaN);
        bMv = scal[1];
        __syncthreads();
    }
    avb[t] = a_sh[t]; avb[t + 1024] = a_sh[t + 1024];
    bvb[t] = b_sh[t]; bvb[t + 1024] = b_sh[t + 1024];
    if (t == 0) { avb[NN] = aNv; bvb[NN] = bMv; }
}

// ========== finalize: P = a_n * K * b_m (+ analytic dustbins) ========
__global__ __launch_bounds__(1024) void finalize_k(
    const unsigned char* __restrict__ Kc,
    const int* __restrict__ flags,
    const float* __restrict__ av, const float* __restrict__ bv,
    float* __restrict__ out)
{
    const int colhalf = blockIdx.x;
    const int rt = blockIdx.y;
    const int batch = blockIdx.z;
    const int t = threadIdx.x;
    const int tsub = t & 255;
    const int rq = t >> 8;
    const int c0 = colhalf * 1024;
    const int r0 = rt * 128;
    const float* avb = av + (size_t)batch * AVP;
    const float* bvb = bv + (size_t)batch * AVP;
    float* ob = out + (size_t)batch * NP * NP;
    const unsigned char* Kb = Kc + (size_t)batch * NN * NN;

    const int f = flags[batch * 256 + rt * 16 + colhalf * 8 + (tsub >> 5)];
    const f32x4 b4 = *(const f32x4*)&bvb[c0 + tsub * 4];
    const float bM = bvb[NN];
    const float aN = avb[NN];

    for (int rr = 0; rr < 32; ++rr) {
        int row = r0 + rr * 4 + rq;
        f32x4 val;
        if (f) {
            float a = avb[row];
            unsigned int kw = *(const unsigned int*)(Kb + (size_t)row * NN + c0 + tsub * 4);
            f32x2 u0 = DEC0(kw), u1 = DEC1(kw);
            val.x = a * u0.x * b4.x; val.y = a * u0.y * b4.y;
            val.z = a * u1.x * b4.z; val.w = a * u1.y * b4.w;
        } else {
            val.x = 0.f; val.y = 0.f; val.z = 0.f; val.w = 0.f;
        }
        __builtin_nontemporal_store(val, (f32x4*)&ob[(size_t)row * NP + c0 + tsub * 4]);
    }
    if (colhalf == 1 && t < 128) {
        int row = r0 + t;
        ob[(size_t)row * NP + NN] = avb[row] * E1 * bM;
    }
    if (rt == 0) {
        int col = c0 + t;
        ob[(size_t)NN * NP + col] = aN * E1 * bvb[col];
        if (colhalf == 1 && t == 0) ob[(size_t)NN * NP + NN] = aN * E1 * bM;
    }
}

// =====================================================================
extern "C" void kernel_launch(void* const* d_in, const int* in_sizes, int n_in,
                              void* d_out, int out_size, void* d_ws, size_t ws_size,
                              hipStream_t stream) {
    const float* d1 = (const float*)d_in[0];
    const float* d2 = (const float*)d_in[1];
    float* out = (float*)d_out;

    const size_t KCB = (size_t)BB * NN * NN;            // 33.5 MB fp8
    unsigned char* Kc = (unsigned char*)d_ws;
    int* flags = (int*)(Kc + KCB);
    float* av = (float*)(flags + BB * 256);
    float* bv = av + (size_t)BB * AVP;

    gemm_fused<<<dim3(8, 8, BB), 512, 0, stream>>>(d1, d2, Kc, flags);
    sinkhorn_iter<<<BB, 1024, 0, stream>>>(Kc, flags, av, bv);
    finalize_k<<<dim3(2, 16, BB), 1024, 0, stream>>>(Kc, flags, av, bv, out);
}

// Round 11
// 75.208 us; speedup vs baseline: 1.1389x; 1.1389x over previous
//
#include <hip/hip_runtime.h>
#include <math.h>

#define BB 8
#define NN 2048
#define DD 256
#define NP 2049
#define AVP 2052
#define E1 0.36787944117144233f
#define PADK 40         // LDS f16 row stride (80 B = 5*16B)
#define ITERS 20

typedef _Float16 f16;
typedef __attribute__((ext_vector_type(8))) _Float16 f16x8;
typedef __attribute__((ext_vector_type(4))) _Float16 f16x4;
typedef __attribute__((ext_vector_type(4))) float f32x4;
typedef __attribute__((ext_vector_type(2))) float f32x2;

#define DEC0(DW) __builtin_amdgcn_cvt_pk_f32_fp8((int)(DW), false)
#define DEC1(DW) __builtin_amdgcn_cvt_pk_f32_fp8((int)(DW), true)

// ------- split_cvt: fp32 -> fp16 copy + row norms (one wave per row) -------
__global__ __launch_bounds__(256) void split_cvt(const float* __restrict__ d1,
                                                 const float* __restrict__ d2,
                                                 f16* __restrict__ A16,
                                                 f16* __restrict__ B16,
                                                 float* __restrict__ n1,
                                                 float* __restrict__ n2) {
    const float* src = blockIdx.z ? d2 : d1;
    f16* dst = blockIdx.z ? B16 : A16;
    float* nn = blockIdx.z ? n2 : n1;
    int b = blockIdx.y;
    int wave = threadIdx.x >> 6, lane = threadIdx.x & 63;
    int row = blockIdx.x * 4 + wave;
    size_t base = ((size_t)b * NN + row) * DD;
    const float4 v = *(const float4*)(src + base + lane * 4);
    float s = v.x * v.x + v.y * v.y + v.z * v.z + v.w * v.w;
    f16x4 h;
    h.x = (f16)v.x; h.y = (f16)v.y; h.z = (f16)v.z; h.w = (f16)v.w;
    *(f16x4*)(dst + base + lane * 4) = h;
    #pragma unroll
    for (int off = 1; off < 64; off <<= 1) s += __shfl_xor(s, off);
    if (lane == 0) nn[b * NN + row] = s;
}

// ==== 256x256-tile fp16 MFMA GEMM + in-place zero-tile P writes ====
// Operand-swapped MFMA: lane&15 = n (row), regs = 4 consecutive m (cols).
// Zero blocks: skip K store, write P=0 tile directly to out, set zflag.
__global__ __launch_bounds__(512) void gemm256(const f16* __restrict__ A16,
                                               const f16* __restrict__ B16,
                                               const float* __restrict__ n1,
                                               const float* __restrict__ n2,
                                               unsigned char* __restrict__ Kc,
                                               int* __restrict__ flags,
                                               int* __restrict__ zflags,
                                               float* __restrict__ out) {
    __shared__ f16 As[256 * PADK];
    __shared__ f16 Bs[256 * PADK];
    __shared__ int anyq[4];
    __shared__ int wnz[8];

    const int b = blockIdx.z;
    const int rt = blockIdx.x, ct = blockIdx.y;
    const int n0 = rt * 256, m0 = ct * 256;
    const int t = threadIdx.x;             // 0..511
    const int wave = t >> 6, lane = t & 63;
    const int wrow = (wave >> 2) * 128;    // 2x4 wave grid: 128x64 per wave
    const int wcol = (wave & 3) * 64;
    const f16* A  = A16 + ((size_t)b * NN + n0) * DD;
    const f16* Bm = B16 + ((size_t)b * NN + m0) * DD;

    const int row1 = t >> 2,         qk1 = (t & 3) * 8;
    const int row2 = (t + 512) >> 2, qk2 = ((t + 512) & 3) * 8;
    if (t < 4) anyq[t] = 0;

    f32x4 zero = {0.f, 0.f, 0.f, 0.f};
    f32x4 acc[8][4];
    #pragma unroll
    for (int i = 0; i < 8; ++i)
        #pragma unroll
        for (int j = 0; j < 4; ++j) acc[i][j] = zero;

    const int rb = lane & 15;
    const int kg = (lane >> 4) * 8;

    for (int k0 = 0; k0 < DD; k0 += 32) {
        f16x8 pa1 = *(const f16x8*)(A  + (size_t)row1 * DD + k0 + qk1);
        f16x8 pa2 = *(const f16x8*)(A  + (size_t)row2 * DD + k0 + qk2);
        f16x8 pb1 = *(const f16x8*)(Bm + (size_t)row1 * DD + k0 + qk1);
        f16x8 pb2 = *(const f16x8*)(Bm + (size_t)row2 * DD + k0 + qk2);
        __syncthreads();
        *(f16x8*)&As[row1 * PADK + qk1] = pa1;
        *(f16x8*)&As[row2 * PADK + qk2] = pa2;
        *(f16x8*)&Bs[row1 * PADK + qk1] = pb1;
        *(f16x8*)&Bs[row2 * PADK + qk2] = pb2;
        __syncthreads();

        f16x8 af[8], bf[4];
        #pragma unroll
        for (int i = 0; i < 8; ++i)
            af[i] = *(const f16x8*)&As[(wrow + i * 16 + rb) * PADK + kg];
        #pragma unroll
        for (int j = 0; j < 4; ++j)
            bf[j] = *(const f16x8*)&Bs[(wcol + j * 16 + rb) * PADK + kg];
        #pragma unroll
        for (int i = 0; i < 8; ++i)
            #pragma unroll
            for (int j = 0; j < 4; ++j)
                acc[i][j] = __builtin_amdgcn_mfma_f32_16x16x32_f16(bf[j], af[i], acc[i][j], 0, 0, 0);
    }

    // ---- epilogue: pack 4 consecutive-m fp8 into dwords ----
    const int mg = (lane >> 4) * 4;
    unsigned int dw[8][4];
    int nzany = 0;
    #pragma unroll
    for (int i = 0; i < 8; ++i) {
        int n = wrow + i * 16 + rb;
        float rn = n1[b * NN + n0 + n];
        #pragma unroll
        for (int j = 0; j < 4; ++j) {
            const f32x4 cn4 = *(const f32x4*)&n2[b * NN + m0 + wcol + j * 16 + mg];
            f32x4 a = acc[i][j];
            float v0 = __expf(-fmaxf(rn + cn4.x - 2.f * a.x, 0.f));
            float v1 = __expf(-fmaxf(rn + cn4.y - 2.f * a.y, 0.f));
            float v2 = __expf(-fmaxf(rn + cn4.z - 2.f * a.z, 0.f));
            float v3 = __expf(-fmaxf(rn + cn4.w - 2.f * a.w, 0.f));
            int p = __builtin_amdgcn_cvt_pk_fp8_f32(v0, v1, 0, false);
            p = __builtin_amdgcn_cvt_pk_fp8_f32(v2, v3, p, true);
            dw[i][j] = (unsigned int)p;
            nzany |= p;
        }
    }
    unsigned long long wm = __ballot(nzany != 0);
    if (lane == 0) wnz[wave] = (wm != 0ULL);
    const int q = (wrow >> 7) * 2 + (wcol >> 7);
    if (nzany) anyq[q] = 1;
    __syncthreads();
    int anyblk = 0;
    #pragma unroll
    for (int k = 0; k < 8; ++k) anyblk |= wnz[k];

    if (anyblk) {
        #pragma unroll
        for (int i = 0; i < 8; ++i) {
            int n = wrow + i * 16 + rb;
            unsigned char* orow = Kc + ((size_t)b * NN + n0 + n) * NN + m0 + wcol + mg;
            #pragma unroll
            for (int j = 0; j < 4; ++j)
                *(unsigned int*)(orow + j * 16) = dw[i][j];
        }
    } else {
        // P == 0 exactly for this tile, independent of a,b: write it now.
        float* ob = out + (size_t)b * NP * NP;
        const int cq = (t & 63) * 4;     // 64 lanes cover one 256-float row
        const int rw = t >> 6;           // 0..7
        #pragma unroll
        for (int k = 0; k < 32; ++k) {
            int row = n0 + rw + k * 8;
            __builtin_nontemporal_store(zero, (f32x4*)&ob[(size_t)row * NP + m0 + cq]);
        }
    }
    if (t < 4) {
        int ti = rt * 2 + (t >> 1);
        int tj = ct * 2 + (t & 1);
        flags[b * 256 + ti * 16 + tj] = anyq[(t >> 1) * 2 + (t & 1)] ? 1 : 0;
    }
    if (t == 0) zflags[b * 64 + rt * 8 + ct] = anyblk ? 0 : 1;
}

// ========== Sinkhorn iterations: one block per batch =================
__global__ __launch_bounds__(1024) void sinkhorn_iter(
    const unsigned char* __restrict__ Kc,
    const int* __restrict__ flags,
    float* __restrict__ av, float* __restrict__ bv)
{
    const int batch = blockIdx.x;
    const int t = threadIdx.x;
    const int lane = t & 63, w = t >> 6;
    __shared__ float a_sh[NN], b_sh[NN], rs_sh[NN];
    __shared__ float p8[128][9];
    __shared__ float wred[16];
    __shared__ float scal[2];
    __shared__ int flg[256];
    __shared__ int rowNZ[16], colNZ[16], anyNZ;

    if (t < 256) flg[t] = flags[batch * 256 + t];
    if (t == 0) anyNZ = 0;
    __syncthreads();
    if (t < 16) {
        int o = 0;
        #pragma unroll
        for (int j = 0; j < 16; ++j) o |= flg[t * 16 + j];
        rowNZ[t] = o;
        if (o) atomicOr(&anyNZ, 1);
    } else if (t < 32) {
        int j = t - 16, o = 0;
        #pragma unroll
        for (int i = 0; i < 16; ++i) o |= flg[i * 16 + j];
        colNZ[j] = o;
    }
    __syncthreads();
    const unsigned char* Kb = Kc + (size_t)batch * NN * NN;
    float* avb = av + (size_t)batch * AVP;
    float* bvb = bv + (size_t)batch * AVP;

    if (!anyNZ) {
        float bMv = 1.f, bcore = 1.f, aNv = 0.f, acore = 0.f;
        for (int it = 0; it < ITERS; ++it) {
            float Sb = 2048.f * bcore + bMv;
            aNv = 2048.f / (E1 * Sb);
            acore = 1.0f / (E1 * bMv);
            float Sa = 2048.f * acore + aNv;
            bcore = 1.0f / (E1 * aNv);
            bMv = 2048.f / (E1 * Sa);
        }
        avb[t] = acore; avb[t + 1024] = acore;
        bvb[t] = bcore; bvb[t + 1024] = bcore;
        if (t == 0) { avb[NN] = aNv; bvb[NN] = bMv; }
        return;
    }

    b_sh[t] = 1.f; b_sh[t + 1024] = 1.f;
    float bMv = 1.f, aNv = 0.f;
    const int r = t >> 3, c8 = (t & 7) * 16;
    __syncthreads();

    for (int it = 0; it < ITERS; ++it) {
        float sb = b_sh[t] + b_sh[t + 1024];
        #pragma unroll
        for (int off = 1; off < 64; off <<= 1) sb += __shfl_xor(sb, off);
        if (lane == 0) wred[w] = sb;
        rs_sh[t] = 0.f; rs_sh[t + 1024] = 0.f;
        __syncthreads();
        if (t == 0) {
            float S = bMv;
            #pragma unroll
            for (int k = 0; k < 16; ++k) S += wred[k];
            scal[0] = 2048.f / (E1 * S);
        }
        __syncthreads();
        aNv = scal[0];

        for (int i = 0; i < 16; ++i) {
            if (!rowNZ[i]) continue;
            float acc = 0.f;
            for (int j = 0; j < 16; ++j) {
                if (!flg[i * 16 + j]) continue;
                const unsigned char* p = Kb + (size_t)(i * 128 + r) * NN + j * 128 + c8;
                uint4 kv = *(const uint4*)p;
                const float* bp = &b_sh[j * 128 + c8];
                unsigned int dwv[4] = {kv.x, kv.y, kv.z, kv.w};
                #pragma unroll
                for (int q = 0; q < 4; ++q) {
                    f32x2 u0 = DEC0(dwv[q]); f32x2 u1 = DEC1(dwv[q]);
                    acc += u0.x * bp[4 * q] + u0.y * bp[4 * q + 1]
                         + u1.x * bp[4 * q + 2] + u1.y * bp[4 * q + 3];
                }
            }
            p8[r][t & 7] = acc;
            __syncthreads();
            if (t < 128) {
                float s = 0.f;
                #pragma unroll
                for (int k = 0; k < 8; ++k) s += p8[t][k];
                rs_sh[i * 128 + t] = s;
            }
            __syncthreads();
        }
        float ebM = E1 * bMv;
        float a0 = 1.0f / (rs_sh[t] + ebM);
        float a1 = 1.0f / (rs_sh[t + 1024] + ebM);
        a_sh[t] = a0; a_sh[t + 1024] = a1;
        float sa = a0 + a1;
        #pragma unroll
        for (int off = 1; off < 64; off <<= 1) sa += __shfl_xor(sa, off);
        if (lane == 0) wred[w] = sa;
        __syncthreads();
        if (t == 0) {
            float S = aNv;
            #pragma unroll
            for (int k = 0; k < 16; ++k) S += wred[k];
            scal[1] = 2048.f / (E1 * S);
        }
        rs_sh[t] = 0.f; rs_sh[t + 1024] = 0.f;
        __syncthreads();

        for (int j = 0; j < 16; ++j) {
            if (!colNZ[j]) continue;
            float acc = 0.f;
            int col = j * 128 + r;
            for (int i = 0; i < 16; ++i) {
                if (!flg[i * 16 + j]) continue;
                #pragma unroll
                for (int e = 0; e < 16; ++e) {
                    int rr2 = i * 128 + c8 + e;
                    f32x2 u = DEC0((unsigned int)Kb[(size_t)rr2 * NN + col]);
                    acc += u.x * a_sh[rr2];
                }
            }
            p8[r][t & 7] = acc;
            __syncthreads();
            if (t < 128) {
                float s = 0.f;
                #pragma unroll
                for (int k = 0; k < 8; ++k) s += p8[t][k];
                rs_sh[j * 128 + t] = s;
            }
            __syncthreads();
        }
        float eaN = E1 * aNv;
        b_sh[t] = 1.0f / (rs_sh[t] + eaN);
        b_sh[t + 1024] = 1.0f / (rs_sh[t + 1024] + eaN);
        bMv = scal[1];
        __syncthreads();
    }
    avb[t] = a_sh[t]; avb[t + 1024] = a_sh[t + 1024];
    bvb[t] = b_sh[t]; bvb[t + 1024] = b_sh[t + 1024];
    if (t == 0) { avb[NN] = aNv; bvb[NN] = bMv; }
}

// ==== finalize: P = a_n*K*b_m for non-zeroed tiles + dustbins ========
__global__ __launch_bounds__(1024) void finalize_k(
    const unsigned char* __restrict__ Kc,
    const int* __restrict__ flags,
    const int* __restrict__ zflags,
    const float* __restrict__ av, const float* __restrict__ bv,
    float* __restrict__ out)
{
    const int colhalf = blockIdx.x;
    const int rt = blockIdx.y;
    const int batch = blockIdx.z;
    const int t = threadIdx.x;
    const int tsub = t & 255;
    const int rq = t >> 8;
    const int c0 = colhalf * 1024;
    const int r0 = rt * 128;
    const float* avb = av + (size_t)batch * AVP;
    const float* bvb = bv + (size_t)batch * AVP;
    float* ob = out + (size_t)batch * NP * NP;
    const unsigned char* Kb = Kc + (size_t)batch * NN * NN;

    const int jt = colhalf * 8 + (tsub >> 5);            // 128-col tile 0..15
    const int f = flags[batch * 256 + rt * 16 + jt];
    const int z = zflags[batch * 64 + (rt >> 1) * 8 + (jt >> 1)];
    const f32x4 b4 = *(const f32x4*)&bvb[c0 + tsub * 4];
    const float bM = bvb[NN];
    const float aN = avb[NN];

    if (!z) {
        for (int rr = 0; rr < 32; ++rr) {
            int row = r0 + rr * 4 + rq;
            f32x4 val;
            if (f) {
                float a = avb[row];
                unsigned int kw = *(const unsigned int*)(Kb + (size_t)row * NN + c0 + tsub * 4);
                f32x2 u0 = DEC0(kw), u1 = DEC1(kw);
                val.x = a * u0.x * b4.x; val.y = a * u0.y * b4.y;
                val.z = a * u1.x * b4.z; val.w = a * u1.y * b4.w;
            } else {
                val.x = 0.f; val.y = 0.f; val.z = 0.f; val.w = 0.f;
            }
            __builtin_nontemporal_store(val, (f32x4*)&ob[(size_t)row * NP + c0 + tsub * 4]);
        }
    }
    if (colhalf == 1 && t < 128) {
        int row = r0 + t;
        ob[(size_t)row * NP + NN] = avb[row] * E1 * bM;
    }
    if (rt == 0) {
        int col = c0 + t;
        ob[(size_t)NN * NP + col] = aN * E1 * bvb[col];
        if (colhalf == 1 && t == 0) ob[(size_t)NN * NP + NN] = aN * E1 * bM;
    }
}

// =====================================================================
extern "C" void kernel_launch(void* const* d_in, const int* in_sizes, int n_in,
                              void* d_out, int out_size, void* d_ws, size_t ws_size,
                              hipStream_t stream) {
    const float* d1 = (const float*)d_in[0];
    const float* d2 = (const float*)d_in[1];
    float* out = (float*)d_out;

    const size_t KCB = (size_t)BB * NN * NN;            // 33.5 MB fp8
    const size_t F16C = (size_t)BB * NN * DD;
    unsigned char* Kc = (unsigned char*)d_ws;
    f16* A16 = (f16*)(Kc + KCB);
    f16* B16 = A16 + F16C;
    int* flags = (int*)(B16 + F16C);                    // BB*256
    int* zflags = flags + BB * 256;                     // BB*64
    float* av = (float*)(zflags + BB * 64);
    float* bv = av + (size_t)BB * AVP;
    float* n1 = bv + (size_t)BB * AVP;
    float* n2 = n1 + (size_t)BB * NN;

    split_cvt<<<dim3(NN / 4, BB, 2), 256, 0, stream>>>(d1, d2, A16, B16, n1, n2);
    gemm256<<<dim3(8, 8, BB), 512, 0, stream>>>(A16, B16, n1, n2, Kc, flags, zflags, out);
    sinkhorn_iter<<<BB, 1024, 0, stream>>>(Kc, flags, av, bv);
    finalize_k<<<dim3(2, 16, BB), 1024, 0, stream>>>(Kc, flags, zflags, av, bv, out);
}

// Round 12
// 74.487 us; speedup vs baseline: 1.1500x; 1.0097x over previous
//
#include <hip/hip_runtime.h>
#include <math.h>

#define BB 8
#define NN 2048
#define DD 256
#define NP 2049
#define AVP 2052
#define E1 0.36787944117144233f
#define PADK 40         // LDS f16 row stride (80 B = 5*16B)
#define ITERS 20

typedef _Float16 f16;
typedef __attribute__((ext_vector_type(8))) _Float16 f16x8;
typedef __attribute__((ext_vector_type(4))) float f32x4;
typedef __attribute__((ext_vector_type(2))) float f32x2;

#define DEC0(DW) __builtin_amdgcn_cvt_pk_f32_fp8((int)(DW), false)
#define DEC1(DW) __builtin_amdgcn_cvt_pk_f32_fp8((int)(DW), true)

// ---- split_cvt: fp32 -> f16 (16B stores) + row norms (32-lane rows) ----
__global__ __launch_bounds__(256) void split_cvt(const float* __restrict__ d1,
                                                 const float* __restrict__ d2,
                                                 f16* __restrict__ A16,
                                                 f16* __restrict__ B16,
                                                 float* __restrict__ n1,
                                                 float* __restrict__ n2) {
    const float* src = blockIdx.z ? d2 : d1;
    f16* dst = blockIdx.z ? B16 : A16;
    float* nn = blockIdx.z ? n2 : n1;
    const int b = blockIdx.y;
    const int row = blockIdx.x * 8 + (threadIdx.x >> 5);
    const int e0 = (threadIdx.x & 31) * 8;
    const size_t base = ((size_t)b * NN + row) * DD + e0;
    f32x4 v0 = *(const f32x4*)(src + base);
    f32x4 v1 = *(const f32x4*)(src + base + 4);
    f16x8 h;
    float s = 0.f;
    #pragma unroll
    for (int e = 0; e < 4; ++e) {
        h[e] = (f16)v0[e]; h[e + 4] = (f16)v1[e];
        s = fmaf(v0[e], v0[e], s);
        s = fmaf(v1[e], v1[e], s);
    }
    *(f16x8*)(dst + base) = h;
    #pragma unroll
    for (int off = 1; off < 32; off <<= 1) s += __shfl_xor(s, off);
    if ((threadIdx.x & 31) == 0) nn[b * NN + row] = s;
}

// ==== 256x256-tile fp16 MFMA GEMM + in-place zero-tile P writes ====
// Software-pipelined staging: K-step k+1 loads issue before MFMA of k.
__global__ __launch_bounds__(512) void gemm256(const f16* __restrict__ A16,
                                               const f16* __restrict__ B16,
                                               const float* __restrict__ n1,
                                               const float* __restrict__ n2,
                                               unsigned char* __restrict__ Kc,
                                               int* __restrict__ flags,
                                               int* __restrict__ zflags,
                                               float* __restrict__ out) {
    __shared__ f16 As[256 * PADK];
    __shared__ f16 Bs[256 * PADK];
    __shared__ int anyq[4];
    __shared__ int wnz[8];

    const int b = blockIdx.z;
    const int rt = blockIdx.x, ct = blockIdx.y;
    const int n0 = rt * 256, m0 = ct * 256;
    const int t = threadIdx.x;             // 0..511
    const int wave = t >> 6, lane = t & 63;
    const int wrow = (wave >> 2) * 128;    // 2x4 wave grid: 128x64 per wave
    const int wcol = (wave & 3) * 64;
    const f16* A  = A16 + ((size_t)b * NN + n0) * DD;
    const f16* Bm = B16 + ((size_t)b * NN + m0) * DD;

    const int row1 = t >> 2,         qk1 = (t & 3) * 8;
    const int row2 = (t + 512) >> 2, qk2 = ((t + 512) & 3) * 8;
    if (t < 4) anyq[t] = 0;

    f32x4 zero = {0.f, 0.f, 0.f, 0.f};
    f32x4 acc[8][4];
    #pragma unroll
    for (int i = 0; i < 8; ++i)
        #pragma unroll
        for (int j = 0; j < 4; ++j) acc[i][j] = zero;

    const int rb = lane & 15;
    const int kg = (lane >> 4) * 8;

    // prologue: load K-step 0
    f16x8 pa1 = *(const f16x8*)(A  + (size_t)row1 * DD + qk1);
    f16x8 pa2 = *(const f16x8*)(A  + (size_t)row2 * DD + qk2);
    f16x8 pb1 = *(const f16x8*)(Bm + (size_t)row1 * DD + qk1);
    f16x8 pb2 = *(const f16x8*)(Bm + (size_t)row2 * DD + qk2);

    for (int k0 = 0; k0 < DD; k0 += 32) {
        __syncthreads();
        *(f16x8*)&As[row1 * PADK + qk1] = pa1;
        *(f16x8*)&As[row2 * PADK + qk2] = pa2;
        *(f16x8*)&Bs[row1 * PADK + qk1] = pb1;
        *(f16x8*)&Bs[row2 * PADK + qk2] = pb2;
        __syncthreads();

        if (k0 + 32 < DD) {   // issue next K-step loads; land under MFMAs
            pa1 = *(const f16x8*)(A  + (size_t)row1 * DD + k0 + 32 + qk1);
            pa2 = *(const f16x8*)(A  + (size_t)row2 * DD + k0 + 32 + qk2);
            pb1 = *(const f16x8*)(Bm + (size_t)row1 * DD + k0 + 32 + qk1);
            pb2 = *(const f16x8*)(Bm + (size_t)row2 * DD + k0 + 32 + qk2);
        }

        f16x8 af[8], bf[4];
        #pragma unroll
        for (int i = 0; i < 8; ++i)
            af[i] = *(const f16x8*)&As[(wrow + i * 16 + rb) * PADK + kg];
        #pragma unroll
        for (int j = 0; j < 4; ++j)
            bf[j] = *(const f16x8*)&Bs[(wcol + j * 16 + rb) * PADK + kg];
        #pragma unroll
        for (int i = 0; i < 8; ++i)
            #pragma unroll
            for (int j = 0; j < 4; ++j)
                acc[i][j] = __builtin_amdgcn_mfma_f32_16x16x32_f16(bf[j], af[i], acc[i][j], 0, 0, 0);
    }

    // ---- epilogue: pack 4 consecutive-m fp8 into dwords ----
    const int mg = (lane >> 4) * 4;
    unsigned int dw[8][4];
    int nzany = 0;
    #pragma unroll
    for (int i = 0; i < 8; ++i) {
        int n = wrow + i * 16 + rb;
        float rn = n1[b * NN + n0 + n];
        #pragma unroll
        for (int j = 0; j < 4; ++j) {
            const f32x4 cn4 = *(const f32x4*)&n2[b * NN + m0 + wcol + j * 16 + mg];
            f32x4 a = acc[i][j];
            float v0 = __expf(-fmaxf(rn + cn4.x - 2.f * a.x, 0.f));
            float v1 = __expf(-fmaxf(rn + cn4.y - 2.f * a.y, 0.f));
            float v2 = __expf(-fmaxf(rn + cn4.z - 2.f * a.z, 0.f));
            float v3 = __expf(-fmaxf(rn + cn4.w - 2.f * a.w, 0.f));
            int p = __builtin_amdgcn_cvt_pk_fp8_f32(v0, v1, 0, false);
            p = __builtin_amdgcn_cvt_pk_fp8_f32(v2, v3, p, true);
            dw[i][j] = (unsigned int)p;
            nzany |= p;
        }
    }
    unsigned long long wm = __ballot(nzany != 0);
    if (lane == 0) wnz[wave] = (wm != 0ULL);
    const int q = (wrow >> 7) * 2 + (wcol >> 7);
    if (nzany) anyq[q] = 1;
    __syncthreads();
    int anyblk = 0;
    #pragma unroll
    for (int k = 0; k < 8; ++k) anyblk |= wnz[k];

    if (anyblk) {
        #pragma unroll
        for (int i = 0; i < 8; ++i) {
            int n = wrow + i * 16 + rb;
            unsigned char* orow = Kc + ((size_t)b * NN + n0 + n) * NN + m0 + wcol + mg;
            #pragma unroll
            for (int j = 0; j < 4; ++j)
                *(unsigned int*)(orow + j * 16) = dw[i][j];
        }
    } else {
        // P == 0 exactly for this tile, independent of a,b: write it now.
        float* ob = out + (size_t)b * NP * NP;
        const int cq = (t & 63) * 4;
        const int rw = t >> 6;
        #pragma unroll
        for (int k = 0; k < 32; ++k) {
            int row = n0 + rw + k * 8;
            __builtin_nontemporal_store(zero, (f32x4*)&ob[(size_t)row * NP + m0 + cq]);
        }
    }
    if (t < 4) {
        int ti = rt * 2 + (t >> 1);
        int tj = ct * 2 + (t & 1);
        flags[b * 256 + ti * 16 + tj] = anyq[(t >> 1) * 2 + (t & 1)] ? 1 : 0;
    }
    if (t == 0) zflags[b * 64 + rt * 8 + ct] = anyblk ? 0 : 1;
}

// ========== Sinkhorn iterations: one block per batch =================
__global__ __launch_bounds__(1024) void sinkhorn_iter(
    const unsigned char* __restrict__ Kc,
    const int* __restrict__ flags,
    float* __restrict__ av, float* __restrict__ bv)
{
    const int batch = blockIdx.x;
    const int t = threadIdx.x;
    const int lane = t & 63, w = t >> 6;
    __shared__ float a_sh[NN], b_sh[NN], rs_sh[NN];
    __shared__ float p8[128][9];
    __shared__ float wred[16];
    __shared__ float scal[2];
    __shared__ int flg[256];
    __shared__ int rowNZ[16], colNZ[16], anyNZ;

    if (t < 256) flg[t] = flags[batch * 256 + t];
    if (t == 0) anyNZ = 0;
    __syncthreads();
    if (t < 16) {
        int o = 0;
        #pragma unroll
        for (int j = 0; j < 16; ++j) o |= flg[t * 16 + j];
        rowNZ[t] = o;
        if (o) atomicOr(&anyNZ, 1);
    } else if (t < 32) {
        int j = t - 16, o = 0;
        #pragma unroll
        for (int i = 0; i < 16; ++i) o |= flg[i * 16 + j];
        colNZ[j] = o;
    }
    __syncthreads();
    const unsigned char* Kb = Kc + (size_t)batch * NN * NN;
    float* avb = av + (size_t)batch * AVP;
    float* bvb = bv + (size_t)batch * AVP;

    if (!anyNZ) {
        float bMv = 1.f, bcore = 1.f, aNv = 0.f, acore = 0.f;
        for (int it = 0; it < ITERS; ++it) {
            float Sb = 2048.f * bcore + bMv;
            aNv = 2048.f / (E1 * Sb);
            acore = 1.0f / (E1 * bMv);
            float Sa = 2048.f * acore + aNv;
            bcore = 1.0f / (E1 * aNv);
            bMv = 2048.f / (E1 * Sa);
        }
        avb[t] = acore; avb[t + 1024] = acore;
        bvb[t] = bcore; bvb[t + 1024] = bcore;
        if (t == 0) { avb[NN] = aNv; bvb[NN] = bMv; }
        return;
    }

    b_sh[t] = 1.f; b_sh[t + 1024] = 1.f;
    float bMv = 1.f, aNv = 0.f;
    const int r = t >> 3, c8 = (t & 7) * 16;
    __syncthreads();

    for (int it = 0; it < ITERS; ++it) {
        float sb = b_sh[t] + b_sh[t + 1024];
        #pragma unroll
        for (int off = 1; off < 64; off <<= 1) sb += __shfl_xor(sb, off);
        if (lane == 0) wred[w] = sb;
        rs_sh[t] = 0.f; rs_sh[t + 1024] = 0.f;
        __syncthreads();
        if (t == 0) {
            float S = bMv;
            #pragma unroll
            for (int k = 0; k < 16; ++k) S += wred[k];
            scal[0] = 2048.f / (E1 * S);
        }
        __syncthreads();
        aNv = scal[0];

        for (int i = 0; i < 16; ++i) {
            if (!rowNZ[i]) continue;
            float acc = 0.f;
            for (int j = 0; j < 16; ++j) {
                if (!flg[i * 16 + j]) continue;
                const unsigned char* p = Kb + (size_t)(i * 128 + r) * NN + j * 128 + c8;
                uint4 kv = *(const uint4*)p;
                const float* bp = &b_sh[j * 128 + c8];
                unsigned int dwv[4] = {kv.x, kv.y, kv.z, kv.w};
                #pragma unroll
                for (int q = 0; q < 4; ++q) {
                    f32x2 u0 = DEC0(dwv[q]); f32x2 u1 = DEC1(dwv[q]);
                    acc += u0.x * bp[4 * q] + u0.y * bp[4 * q + 1]
                         + u1.x * bp[4 * q + 2] + u1.y * bp[4 * q + 3];
                }
            }
            p8[r][t & 7] = acc;
            __syncthreads();
            if (t < 128) {
                float s = 0.f;
                #pragma unroll
                for (int k = 0; k < 8; ++k) s += p8[t][k];
                rs_sh[i * 128 + t] = s;
            }
            __syncthreads();
        }
        float ebM = E1 * bMv;
        float a0 = 1.0f / (rs_sh[t] + ebM);
        float a1 = 1.0f / (rs_sh[t + 1024] + ebM);
        a_sh[t] = a0; a_sh[t + 1024] = a1;
        float sa = a0 + a1;
        #pragma unroll
        for (int off = 1; off < 64; off <<= 1) sa += __shfl_xor(sa, off);
        if (lane == 0) wred[w] = sa;
        __syncthreads();
        if (t == 0) {
            float S = aNv;
            #pragma unroll
            for (int k = 0; k < 16; ++k) S += wred[k];
            scal[1] = 2048.f / (E1 * S);
        }
        rs_sh[t] = 0.f; rs_sh[t + 1024] = 0.f;
        __syncthreads();

        for (int j = 0; j < 16; ++j) {
            if (!colNZ[j]) continue;
            float acc = 0.f;
            int col = j * 128 + r;
            for (int i = 0; i < 16; ++i) {
                if (!flg[i * 16 + j]) continue;
                #pragma unroll
                for (int e = 0; e < 16; ++e) {
                    int rr2 = i * 128 + c8 + e;
                    f32x2 u = DEC0((unsigned int)Kb[(size_t)rr2 * NN + col]);
                    acc += u.x * a_sh[rr2];
                }
            }
            p8[r][t & 7] = acc;
            __syncthreads();
            if (t < 128) {
                float s = 0.f;
                #pragma unroll
                for (int k = 0; k < 8; ++k) s += p8[t][k];
                rs_sh[j * 128 + t] = s;
            }
            __syncthreads();
        }
        float eaN = E1 * aNv;
        b_sh[t] = 1.0f / (rs_sh[t] + eaN);
        b_sh[t + 1024] = 1.0f / (rs_sh[t + 1024] + eaN);
        bMv = scal[1];
        __syncthreads();
    }
    avb[t] = a_sh[t]; avb[t + 1024] = a_sh[t + 1024];
    bvb[t] = b_sh[t]; bvb[t + 1024] = b_sh[t + 1024];
    if (t == 0) { avb[NN] = aNv; bvb[NN] = bMv; }
}

// ==== finalize: P = a_n*K*b_m for non-zeroed tiles + dustbins ========
__global__ __launch_bounds__(1024) void finalize_k(
    const unsigned char* __restrict__ Kc,
    const int* __restrict__ flags,
    const int* __restrict__ zflags,
    const float* __restrict__ av, const float* __restrict__ bv,
    float* __restrict__ out)
{
    const int colhalf = blockIdx.x;
    const int rt = blockIdx.y;
    const int batch = blockIdx.z;
    const int t = threadIdx.x;
    const int tsub = t & 255;
    const int rq = t >> 8;
    const int c0 = colhalf * 1024;
    const int r0 = rt * 128;
    const float* avb = av + (size_t)batch * AVP;
    const float* bvb = bv + (size_t)batch * AVP;
    float* ob = out + (size_t)batch * NP * NP;
    const unsigned char* Kb = Kc + (size_t)batch * NN * NN;

    const int jt = colhalf * 8 + (tsub >> 5);
    const int f = flags[batch * 256 + rt * 16 + jt];
    const int z = zflags[batch * 64 + (rt >> 1) * 8 + (jt >> 1)];
    const f32x4 b4 = *(const f32x4*)&bvb[c0 + tsub * 4];
    const float bM = bvb[NN];
    const float aN = avb[NN];

    if (!z) {
        for (int rr = 0; rr < 32; ++rr) {
            int row = r0 + rr * 4 + rq;
            f32x4 val;
            if (f) {
                float a = avb[row];
                unsigned int kw = *(const unsigned int*)(Kb + (size_t)row * NN + c0 + tsub * 4);
                f32x2 u0 = DEC0(kw), u1 = DEC1(kw);
                val.x = a * u0.x * b4.x; val.y = a * u0.y * b4.y;
                val.z = a * u1.x * b4.z; val.w = a * u1.y * b4.w;
            } else {
                val.x = 0.f; val.y = 0.f; val.z = 0.f; val.w = 0.f;
            }
            __builtin_nontemporal_store(val, (f32x4*)&ob[(size_t)row * NP + c0 + tsub * 4]);
        }
    }
    if (colhalf == 1 && t < 128) {
        int row = r0 + t;
        ob[(size_t)row * NP + NN] = avb[row] * E1 * bM;
    }
    if (rt == 0) {
        int col = c0 + t;
        ob[(size_t)NN * NP + col] = aN * E1 * bvb[col];
        if (colhalf == 1 && t == 0) ob[(size_t)NN * NP + NN] = aN * E1 * bM;
    }
}

// =====================================================================
extern "C" void kernel_launch(void* const* d_in, const int* in_sizes, int n_in,
                              void* d_out, int out_size, void* d_ws, size_t ws_size,
                              hipStream_t stream) {
    const float* d1 = (const float*)d_in[0];
    const float* d2 = (const float*)d_in[1];
    float* out = (float*)d_out;

    const size_t KCB = (size_t)BB * NN * NN;            // 33.5 MB fp8
    const size_t F16C = (size_t)BB * NN * DD;
    unsigned char* Kc = (unsigned char*)d_ws;
    f16* A16 = (f16*)(Kc + KCB);
    f16* B16 = A16 + F16C;
    int* flags = (int*)(B16 + F16C);                    // BB*256
    int* zflags = flags + BB * 256;                     // BB*64
    float* av = (float*)(zflags + BB * 64);
    float* bv = av + (size_t)BB * AVP;
    float* n1 = bv + (size_t)BB * AVP;
    float* n2 = n1 + (size_t)BB * NN;

    split_cvt<<<dim3(NN / 8, BB, 2), 256, 0, stream>>>(d1, d2, A16, B16, n1, n2);
    gemm256<<<dim3(8, 8, BB), 512, 0, stream>>>(A16, B16, n1, n2, Kc, flags, zflags, out);
    sinkhorn_iter<<<BB, 1024, 0, stream>>>(Kc, flags, av, bv);
    finalize_k<<<dim3(2, 16, BB), 1024, 0, stream>>>(Kc, flags, zflags, av, bv, out);
}

// Round 13
// 61.055 us; speedup vs baseline: 1.4030x; 1.2200x over previous
//
#include <hip/hip_runtime.h>
#include <math.h>

#define BB 8
#define NN 2048
#define DD 256
#define NP 2049
#define AVP 2052
#define E1 0.36787944117144233f
#define PADK 40         // LDS f16 row stride (80 B = 5*16B)
#define ITERS 20

typedef _Float16 f16;
typedef __attribute__((ext_vector_type(8))) _Float16 f16x8;
typedef __attribute__((ext_vector_type(4))) float f32x4;
typedef __attribute__((ext_vector_type(2))) float f32x2;

#define DEC0(DW) __builtin_amdgcn_cvt_pk_f32_fp8((int)(DW), false)
#define DEC1(DW) __builtin_amdgcn_cvt_pk_f32_fp8((int)(DW), true)

// ---- split_cvt: fp32 -> f16 (16B stores) + row norms (32-lane rows) ----
__global__ __launch_bounds__(256) void split_cvt(const float* __restrict__ d1,
                                                 const float* __restrict__ d2,
                                                 f16* __restrict__ A16,
                                                 f16* __restrict__ B16,
                                                 float* __restrict__ n1,
                                                 float* __restrict__ n2) {
    const float* src = blockIdx.z ? d2 : d1;
    f16* dst = blockIdx.z ? B16 : A16;
    float* nn = blockIdx.z ? n2 : n1;
    const int b = blockIdx.y;
    const int row = blockIdx.x * 8 + (threadIdx.x >> 5);
    const int e0 = (threadIdx.x & 31) * 8;
    const size_t base = ((size_t)b * NN + row) * DD + e0;
    f32x4 v0 = *(const f32x4*)(src + base);
    f32x4 v1 = *(const f32x4*)(src + base + 4);
    f16x8 h;
    float s = 0.f;
    #pragma unroll
    for (int e = 0; e < 4; ++e) {
        h[e] = (f16)v0[e]; h[e + 4] = (f16)v1[e];
        s = fmaf(v0[e], v0[e], s);
        s = fmaf(v1[e], v1[e], s);
    }
    *(f16x8*)(dst + base) = h;
    #pragma unroll
    for (int off = 1; off < 32; off <<= 1) s += __shfl_xor(s, off);
    if ((threadIdx.x & 31) == 0) nn[b * NN + row] = s;
}

// ==== 128x256-tile fp16 MFMA GEMM, dbuf 1-barrier K-loop, =========
// ==== in-loop unconditional P-zero stores (overwritten later  =====
// ==== by finalize for nonzero tiles).                          =====
__global__ __launch_bounds__(512) void gemm128(const f16* __restrict__ A16,
                                               const f16* __restrict__ B16,
                                               const float* __restrict__ n1,
                                               const float* __restrict__ n2,
                                               unsigned char* __restrict__ Kc,
                                               int* __restrict__ flags,
                                               int* __restrict__ zflags,
                                               float* __restrict__ out) {
    __shared__ f16 As[2][128 * PADK];
    __shared__ f16 Bs[2][256 * PADK];
    __shared__ int anyq[2];

    const int b = blockIdx.z;
    const int rt = blockIdx.x, ct = blockIdx.y;   // xcd = rt % 8 (A panels pinned)
    const int n0 = rt * 128, m0 = ct * 256;
    const int t = threadIdx.x;                    // 0..511
    const int wave = t >> 6, lane = t & 63;
    const int wrow = (wave >> 2) * 64;            // 2x4 wave grid: 64x64 out/wave
    const int wcol = (wave & 3) * 64;
    const f16* A  = A16 + ((size_t)b * NN + n0) * DD;
    const f16* Bm = B16 + ((size_t)b * NN + m0) * DD;
    float* ob = out + (size_t)b * NP * NP;

    const int rowA = t >> 2, qk = (t & 3) * 8;    // A: 128 rows x 4 chunks
    const int rowB2 = 128 + rowA;                 // B: 256 rows, 2 chunks/thread
    if (t < 2) anyq[t] = 0;

    f32x4 zero = {0.f, 0.f, 0.f, 0.f};
    f32x4 acc[4][4];
    #pragma unroll
    for (int i = 0; i < 4; ++i)
        #pragma unroll
        for (int j = 0; j < 4; ++j) acc[i][j] = zero;

    const int rb = lane & 15;
    const int kg = (lane >> 4) * 8;

    // prologue: stage step 0, start loads for step 1
    f16x8 pa  = *(const f16x8*)(A  + (size_t)rowA  * DD + qk);
    f16x8 pb1 = *(const f16x8*)(Bm + (size_t)rowA  * DD + qk);
    f16x8 pb2 = *(const f16x8*)(Bm + (size_t)rowB2 * DD + qk);
    *(f16x8*)&As[0][rowA  * PADK + qk] = pa;
    *(f16x8*)&Bs[0][rowA  * PADK + qk] = pb1;
    *(f16x8*)&Bs[0][rowB2 * PADK + qk] = pb2;
    pa  = *(const f16x8*)(A  + (size_t)rowA  * DD + 32 + qk);
    pb1 = *(const f16x8*)(Bm + (size_t)rowA  * DD + 32 + qk);
    pb2 = *(const f16x8*)(Bm + (size_t)rowB2 * DD + 32 + qk);
    __syncthreads();

    const int pcol = m0 + (t & 31) * 8;
    const int prow0 = n0 + (t >> 5);
    int cur = 0;

    for (int s = 0; s < 8; ++s) {
        // compute current buffer
        f16x8 af[4], bf[4];
        #pragma unroll
        for (int f = 0; f < 4; ++f) {
            af[f] = *(const f16x8*)&As[cur][(wrow + f * 16 + rb) * PADK + kg];
            bf[f] = *(const f16x8*)&Bs[cur][(wcol + f * 16 + rb) * PADK + kg];
        }
        #pragma unroll
        for (int i = 0; i < 4; ++i)
            #pragma unroll
            for (int j = 0; j < 4; ++j)
                acc[i][j] = __builtin_amdgcn_mfma_f32_16x16x32_f16(bf[j], af[i], acc[i][j], 0, 0, 0);

        // unconditional P=0 pre-write for this tile (16 rows per step),
        // drains under MFMA/staging; finalize overwrites nonzero tiles.
        {
            int row = prow0 + s * 16;
            __builtin_nontemporal_store(zero, (f32x4*)&ob[(size_t)row * NP + pcol]);
            __builtin_nontemporal_store(zero, (f32x4*)&ob[(size_t)row * NP + pcol + 4]);
        }

        if (s < 7) {
            // write next buffer (regs loaded one step ago)
            *(f16x8*)&As[cur ^ 1][rowA  * PADK + qk] = pa;
            *(f16x8*)&Bs[cur ^ 1][rowA  * PADK + qk] = pb1;
            *(f16x8*)&Bs[cur ^ 1][rowB2 * PADK + qk] = pb2;
            if (s < 6) {
                int k0 = (s + 2) * 32;
                pa  = *(const f16x8*)(A  + (size_t)rowA  * DD + k0 + qk);
                pb1 = *(const f16x8*)(Bm + (size_t)rowA  * DD + k0 + qk);
                pb2 = *(const f16x8*)(Bm + (size_t)rowB2 * DD + k0 + qk);
            }
        }
        __syncthreads();
        cur ^= 1;
    }

    // ---- epilogue: fp8 pack; store K only if tile nonzero ----
    const int mg = (lane >> 4) * 4;
    unsigned int dw[4][4];
    int nzany = 0;
    #pragma unroll
    for (int i = 0; i < 4; ++i) {
        int n = wrow + i * 16 + rb;
        float rn = n1[b * NN + n0 + n];
        #pragma unroll
        for (int j = 0; j < 4; ++j) {
            const f32x4 cn4 = *(const f32x4*)&n2[b * NN + m0 + wcol + j * 16 + mg];
            f32x4 a = acc[i][j];
            float v0 = __expf(-fmaxf(rn + cn4.x - 2.f * a.x, 0.f));
            float v1 = __expf(-fmaxf(rn + cn4.y - 2.f * a.y, 0.f));
            float v2 = __expf(-fmaxf(rn + cn4.z - 2.f * a.z, 0.f));
            float v3 = __expf(-fmaxf(rn + cn4.w - 2.f * a.w, 0.f));
            int p = __builtin_amdgcn_cvt_pk_fp8_f32(v0, v1, 0, false);
            p = __builtin_amdgcn_cvt_pk_fp8_f32(v2, v3, p, true);
            dw[i][j] = (unsigned int)p;
            nzany |= p;
        }
    }
    if (nzany) anyq[wcol >> 7] = 1;
    __syncthreads();
    const int anyblk = anyq[0] | anyq[1];

    if (anyblk) {
        #pragma unroll
        for (int i = 0; i < 4; ++i) {
            int n = wrow + i * 16 + rb;
            unsigned char* orow = Kc + ((size_t)b * NN + n0 + n) * NN + m0 + wcol + mg;
            #pragma unroll
            for (int j = 0; j < 4; ++j)
                *(unsigned int*)(orow + j * 16) = dw[i][j];
        }
    }
    if (t < 2) flags[b * 256 + rt * 16 + ct * 2 + t] = anyq[t] ? 1 : 0;
    if (t == 0) zflags[b * 128 + rt * 8 + ct] = anyblk ? 0 : 1;
}

// ========== Sinkhorn iterations: one block per batch =================
__global__ __launch_bounds__(1024) void sinkhorn_iter(
    const unsigned char* __restrict__ Kc,
    const int* __restrict__ flags,
    float* __restrict__ av, float* __restrict__ bv)
{
    const int batch = blockIdx.x;
    const int t = threadIdx.x;
    const int lane = t & 63, w = t >> 6;
    __shared__ float a_sh[NN], b_sh[NN], rs_sh[NN];
    __shared__ float p8[128][9];
    __shared__ float wred[16];
    __shared__ float scal[2];
    __shared__ int flg[256];
    __shared__ int rowNZ[16], colNZ[16], anyNZ;

    if (t < 256) flg[t] = flags[batch * 256 + t];
    if (t == 0) anyNZ = 0;
    __syncthreads();
    if (t < 16) {
        int o = 0;
        #pragma unroll
        for (int j = 0; j < 16; ++j) o |= flg[t * 16 + j];
        rowNZ[t] = o;
        if (o) atomicOr(&anyNZ, 1);
    } else if (t < 32) {
        int j = t - 16, o = 0;
        #pragma unroll
        for (int i = 0; i < 16; ++i) o |= flg[i * 16 + j];
        colNZ[j] = o;
    }
    __syncthreads();
    const unsigned char* Kb = Kc + (size_t)batch * NN * NN;
    float* avb = av + (size_t)batch * AVP;
    float* bvb = bv + (size_t)batch * AVP;

    if (!anyNZ) {
        float bMv = 1.f, bcore = 1.f, aNv = 0.f, acore = 0.f;
        for (int it = 0; it < ITERS; ++it) {
            float Sb = 2048.f * bcore + bMv;
            aNv = 2048.f / (E1 * Sb);
            acore = 1.0f / (E1 * bMv);
            float Sa = 2048.f * acore + aNv;
            bcore = 1.0f / (E1 * aNv);
            bMv = 2048.f / (E1 * Sa);
        }
        avb[t] = acore; avb[t + 1024] = acore;
        bvb[t] = bcore; bvb[t + 1024] = bcore;
        if (t == 0) { avb[NN] = aNv; bvb[NN] = bMv; }
        return;
    }

    b_sh[t] = 1.f; b_sh[t + 1024] = 1.f;
    float bMv = 1.f, aNv = 0.f;
    const int r = t >> 3, c8 = (t & 7) * 16;
    __syncthreads();

    for (int it = 0; it < ITERS; ++it) {
        float sb = b_sh[t] + b_sh[t + 1024];
        #pragma unroll
        for (int off = 1; off < 64; off <<= 1) sb += __shfl_xor(sb, off);
        if (lane == 0) wred[w] = sb;
        rs_sh[t] = 0.f; rs_sh[t + 1024] = 0.f;
        __syncthreads();
        if (t == 0) {
            float S = bMv;
            #pragma unroll
            for (int k = 0; k < 16; ++k) S += wred[k];
            scal[0] = 2048.f / (E1 * S);
        }
        __syncthreads();
        aNv = scal[0];

        for (int i = 0; i < 16; ++i) {
            if (!rowNZ[i]) continue;
            float acc = 0.f;
            for (int j = 0; j < 16; ++j) {
                if (!flg[i * 16 + j]) continue;
                const unsigned char* p = Kb + (size_t)(i * 128 + r) * NN + j * 128 + c8;
                uint4 kv = *(const uint4*)p;
                const float* bp = &b_sh[j * 128 + c8];
                unsigned int dwv[4] = {kv.x, kv.y, kv.z, kv.w};
                #pragma unroll
                for (int q = 0; q < 4; ++q) {
                    f32x2 u0 = DEC0(dwv[q]); f32x2 u1 = DEC1(dwv[q]);
                    acc += u0.x * bp[4 * q] + u0.y * bp[4 * q + 1]
                         + u1.x * bp[4 * q + 2] + u1.y * bp[4 * q + 3];
                }
            }
            p8[r][t & 7] = acc;
            __syncthreads();
            if (t < 128) {
                float s = 0.f;
                #pragma unroll
                for (int k = 0; k < 8; ++k) s += p8[t][k];
                rs_sh[i * 128 + t] = s;
            }
            __syncthreads();
        }
        float ebM = E1 * bMv;
        float a0 = 1.0f / (rs_sh[t] + ebM);
        float a1 = 1.0f / (rs_sh[t + 1024] + ebM);
        a_sh[t] = a0; a_sh[t + 1024] = a1;
        float sa = a0 + a1;
        #pragma unroll
        for (int off = 1; off < 64; off <<= 1) sa += __shfl_xor(sa, off);
        if (lane == 0) wred[w] = sa;
        __syncthreads();
        if (t == 0) {
            float S = aNv;
            #pragma unroll
            for (int k = 0; k < 16; ++k) S += wred[k];
            scal[1] = 2048.f / (E1 * S);
        }
        rs_sh[t] = 0.f; rs_sh[t + 1024] = 0.f;
        __syncthreads();

        for (int j = 0; j < 16; ++j) {
            if (!colNZ[j]) continue;
            float acc = 0.f;
            int col = j * 128 + r;
            for (int i = 0; i < 16; ++i) {
                if (!flg[i * 16 + j]) continue;
                #pragma unroll
                for (int e = 0; e < 16; ++e) {
                    int rr2 = i * 128 + c8 + e;
                    f32x2 u = DEC0((unsigned int)Kb[(size_t)rr2 * NN + col]);
                    acc += u.x * a_sh[rr2];
                }
            }
            p8[r][t & 7] = acc;
            __syncthreads();
            if (t < 128) {
                float s = 0.f;
                #pragma unroll
                for (int k = 0; k < 8; ++k) s += p8[t][k];
                rs_sh[j * 128 + t] = s;
            }
            __syncthreads();
        }
        float eaN = E1 * aNv;
        b_sh[t] = 1.0f / (rs_sh[t] + eaN);
        b_sh[t + 1024] = 1.0f / (rs_sh[t + 1024] + eaN);
        bMv = scal[1];
        __syncthreads();
    }
    avb[t] = a_sh[t]; avb[t + 1024] = a_sh[t + 1024];
    bvb[t] = b_sh[t]; bvb[t + 1024] = b_sh[t + 1024];
    if (t == 0) { avb[NN] = aNv; bvb[NN] = bMv; }
}

// ==== finalize: P = a_n*K*b_m for non-zeroed tiles + dustbins ========
__global__ __launch_bounds__(1024) void finalize_k(
    const unsigned char* __restrict__ Kc,
    const int* __restrict__ flags,
    const int* __restrict__ zflags,
    const float* __restrict__ av, const float* __restrict__ bv,
    float* __restrict__ out)
{
    const int colhalf = blockIdx.x;
    const int rt = blockIdx.y;
    const int batch = blockIdx.z;
    const int t = threadIdx.x;
    const int tsub = t & 255;
    const int rq = t >> 8;
    const int c0 = colhalf * 1024;
    const int r0 = rt * 128;
    const float* avb = av + (size_t)batch * AVP;
    const float* bvb = bv + (size_t)batch * AVP;
    float* ob = out + (size_t)batch * NP * NP;
    const unsigned char* Kb = Kc + (size_t)batch * NN * NN;

    const int jt = colhalf * 8 + (tsub >> 5);            // 128-col tile 0..15
    const int f = flags[batch * 256 + rt * 16 + jt];
    const int z = zflags[batch * 128 + rt * 8 + (jt >> 1)];
    const f32x4 b4 = *(const f32x4*)&bvb[c0 + tsub * 4];
    const float bM = bvb[NN];
    const float aN = avb[NN];

    if (!z) {
        for (int rr = 0; rr < 32; ++rr) {
            int row = r0 + rr * 4 + rq;
            f32x4 val;
            if (f) {
                float a = avb[row];
                unsigned int kw = *(const unsigned int*)(Kb + (size_t)row * NN + c0 + tsub * 4);
                f32x2 u0 = DEC0(kw), u1 = DEC1(kw);
                val.x = a * u0.x * b4.x; val.y = a * u0.y * b4.y;
                val.z = a * u1.x * b4.z; val.w = a * u1.y * b4.w;
            } else {
                val.x = 0.f; val.y = 0.f; val.z = 0.f; val.w = 0.f;
            }
            __builtin_nontemporal_store(val, (f32x4*)&ob[(size_t)row * NP + c0 + tsub * 4]);
        }
    }
    if (colhalf == 1 && t < 128) {
        int row = r0 + t;
        ob[(size_t)row * NP + NN] = avb[row] * E1 * bM;
    }
    if (rt == 0) {
        int col = c0 + t;
        ob[(size_t)NN * NP + col] = aN * E1 * bvb[col];
        if (colhalf == 1 && t == 0) ob[(size_t)NN * NP + NN] = aN * E1 * bM;
    }
}

// =====================================================================
extern "C" void kernel_launch(void* const* d_in, const int* in_sizes, int n_in,
                              void* d_out, int out_size, void* d_ws, size_t ws_size,
                              hipStream_t stream) {
    const float* d1 = (const float*)d_in[0];
    const float* d2 = (const float*)d_in[1];
    float* out = (float*)d_out;

    const size_t KCB = (size_t)BB * NN * NN;            // 33.5 MB fp8
    const size_t F16C = (size_t)BB * NN * DD;
    unsigned char* Kc = (unsigned char*)d_ws;
    f16* A16 = (f16*)(Kc + KCB);
    f16* B16 = A16 + F16C;
    int* flags = (int*)(B16 + F16C);                    // BB*256
    int* zflags = flags + BB * 256;                     // BB*128
    float* av = (float*)(zflags + BB * 128);
    float* bv = av + (size_t)BB * AVP;
    float* n1 = bv + (size_t)BB * AVP;
    float* n2 = n1 + (size_t)BB * NN;

    split_cvt<<<dim3(NN / 8, BB, 2), 256, 0, stream>>>(d1, d2, A16, B16, n1, n2);
    gemm128<<<dim3(16, 8, BB), 512, 0, stream>>>(A16, B16, n1, n2, Kc, flags, zflags, out);
    sinkhorn_iter<<<BB, 1024, 0, stream>>>(Kc, flags, av, bv);
    finalize_k<<<dim3(2, 16, BB), 1024, 0, stream>>>(Kc, flags, zflags, av, bv, out);
}